// Round 2
// baseline (9.667 us; speedup 1.0000x reference)
//
#include <hip/hip_runtime.h>
#include <math.h>

// TLSTMWithID — B=512, S=512, F=128, H=256, E=16, NC=3, FIN=143.
//
// KEY SEMANTIC FACT (from the JAX reference): the scan's step multiplies BOTH
// carries (h, c) by mask_t = (t < lengths[b]) at EVERY step, including the
// final one (t = S-1). lengths = randint(0, S) ∈ [0, S-1], so the final-step
// mask is 0 for every row -> final hidden state is exactly zero -> the output
// is exactly b_out broadcast.
//
// Round-2 change: shrink dispatch from 512 wg to 8 wg (one per XCD). Each
// block owns 64 rows = 192 outputs -> one predicated store per thread on the
// fast path. The fully general cooperative TLSTM fallback (len >= S, which
// the bench distribution can never produce) runs per-row inside a
// block-uniform loop, preserving exact semantics for arbitrary inputs.

namespace {

constexpr int kB   = 512;
constexpr int kS   = 512;
constexpr int kF   = 128;
constexpr int kH   = 256;
constexpr int kE   = 16;
constexpr int kNC  = 3;
constexpr int kFIN = kF - 1 + kE;  // 143

constexpr int kBlocks       = 8;
constexpr int kRowsPerBlock = kB / kBlocks;  // 64
constexpr int kOutsPerBlock = kRowsPerBlock * kNC;  // 192 (<= 256 threads)

__device__ __forceinline__ float sigf(float v) {
    return 1.0f / (1.0f + expf(-v));
}

__global__ __launch_bounds__(kH) void tlstm_kernel(
    const float* __restrict__ x,            // (B, S, F)
    const int*   __restrict__ lengths,      // (B,)
    const int*   __restrict__ id_indices,   // (B,)
    const float* __restrict__ id_emb,       // (NID, E)
    const float* __restrict__ W_in,         // (H, FIN)
    const float* __restrict__ b_in,         // (H,)
    const float* __restrict__ W_dec,        // (H, 1)
    const float* __restrict__ b_dec,        // (H,)
    const float* __restrict__ W_ih,         // (4H, H)
    const float* __restrict__ b_ih,         // (4H,)
    const float* __restrict__ W_hh,         // (4H, H)
    const float* __restrict__ b_hh,         // (4H,)
    const float* __restrict__ W_out,        // (NC, H)
    const float* __restrict__ b_out,        // (NC,)
    float* __restrict__ out)                // (B, NC)
{
    const int tid     = threadIdx.x;                  // 0..255
    const int rowBase = blockIdx.x * kRowsPerBlock;

    // ---- Fast path: rows whose final mask is 0 (len < S) => out = b_out. ----
    if (tid < kOutsPerBlock) {
        const int b  = rowBase + tid / kNC;
        const int cc = tid - (tid / kNC) * kNC;
        if (lengths[b] < kS) out[b * kNC + cc] = b_out[cc];
    }

    // ---- General fallback: cooperative TLSTM for any row with len >= S. ----
    // Unreachable with the bench's input distribution; block-uniform branch.
    __shared__ float sh_fcat[kFIN];   // [feats(127) | id_emb(16)]
    __shared__ float sh_emb[kH];
    __shared__ float sh_h[kH];

    for (int b = rowBase; b < rowBase + kRowsPerBlock; ++b) {
        const int len = lengths[b];   // block-uniform
        if (len < kS) continue;

        float c = 0.0f;
        sh_h[tid] = 0.0f;
        const int idx = id_indices[b];
        if (tid < kE) sh_fcat[kF - 1 + tid] = id_emb[(size_t)idx * kE + tid];
        __syncthreads();

        for (int t = 0; t < kS; ++t) {
            const float* xt = x + ((size_t)b * kS + t) * kF;
            if (tid < kF - 1) sh_fcat[tid] = xt[tid];
            __syncthreads();
            const float dt = xt[kF - 1];

            float acc = b_in[tid];
            const float* wrow = W_in + (size_t)tid * kFIN;
            #pragma unroll 11
            for (int f = 0; f < kFIN; ++f) acc += sh_fcat[f] * wrow[f];
            sh_emb[tid] = tanhf(acc);

            const float gamma = sigf(dt * W_dec[tid] + b_dec[tid]);
            c *= gamma;
            __syncthreads();

            float gi = b_ih[0 * kH + tid] + b_hh[0 * kH + tid];
            float gf = b_ih[1 * kH + tid] + b_hh[1 * kH + tid];
            float gg = b_ih[2 * kH + tid] + b_hh[2 * kH + tid];
            float go = b_ih[3 * kH + tid] + b_hh[3 * kH + tid];
            const float* wih_i = W_ih + (size_t)(0 * kH + tid) * kH;
            const float* wih_f = W_ih + (size_t)(1 * kH + tid) * kH;
            const float* wih_g = W_ih + (size_t)(2 * kH + tid) * kH;
            const float* wih_o = W_ih + (size_t)(3 * kH + tid) * kH;
            const float* whh_i = W_hh + (size_t)(0 * kH + tid) * kH;
            const float* whh_f = W_hh + (size_t)(1 * kH + tid) * kH;
            const float* whh_g = W_hh + (size_t)(2 * kH + tid) * kH;
            const float* whh_o = W_hh + (size_t)(3 * kH + tid) * kH;
            for (int hh = 0; hh < kH; ++hh) {
                const float e  = sh_emb[hh];
                const float hp = sh_h[hh];
                gi += e * wih_i[hh] + hp * whh_i[hh];
                gf += e * wih_f[hh] + hp * whh_f[hh];
                gg += e * wih_g[hh] + hp * whh_g[hh];
                go += e * wih_o[hh] + hp * whh_o[hh];
            }

            const float iv = sigf(gi);
            const float fv = sigf(gf);
            const float ov = sigf(go);
            const float gv = tanhf(gg);
            c = fv * c + iv * gv;
            float hv = ov * tanhf(c);

            const float m = (t < len) ? 1.0f : 0.0f;
            c *= m;
            hv *= m;
            __syncthreads();
            sh_h[tid] = hv;
            __syncthreads();
        }

        if (tid < kNC) {
            float acc = b_out[tid];
            const float* wrow = W_out + (size_t)tid * kH;
            for (int hh = 0; hh < kH; ++hh) acc += sh_h[hh] * wrow[hh];
            out[b * kNC + tid] = acc;
        }
        __syncthreads();
    }
}

}  // namespace

extern "C" void kernel_launch(void* const* d_in, const int* in_sizes, int n_in,
                              void* d_out, int out_size, void* d_ws, size_t ws_size,
                              hipStream_t stream) {
    const float* x          = (const float*)d_in[0];
    const int*   lengths    = (const int*)  d_in[1];
    const int*   id_indices = (const int*)  d_in[2];
    const float* id_emb     = (const float*)d_in[3];
    const float* W_in       = (const float*)d_in[4];
    const float* b_in       = (const float*)d_in[5];
    const float* W_dec      = (const float*)d_in[6];
    const float* b_dec      = (const float*)d_in[7];
    const float* W_ih       = (const float*)d_in[8];
    const float* b_ih       = (const float*)d_in[9];
    const float* W_hh       = (const float*)d_in[10];
    const float* b_hh       = (const float*)d_in[11];
    const float* W_out      = (const float*)d_in[12];
    const float* b_out      = (const float*)d_in[13];
    float* out = (float*)d_out;

    tlstm_kernel<<<dim3(kBlocks), dim3(kH), 0, stream>>>(
        x, lengths, id_indices, id_emb, W_in, b_in, W_dec, b_dec,
        W_ih, b_ih, W_hh, b_hh, W_out, b_out, out);
}